// Round 1
// baseline (368.062 us; speedup 1.0000x reference)
//
#include <hip/hip_runtime.h>

// ZBL pair potential + segment-sum into per-atom energies.
// Inputs (setup_inputs order):
//   d_in[0] Z            (4,)        float32
//   d_in[1] r            (E,)        float32   E = 6,400,000
//   d_in[2] per_atom_energy (N,1)    float32   N = 100,000
//   d_in[3] atom_types   (N,)        int32 (harness narrows int64 -> int32)
//   d_in[4] edge_index   (2,E)       int32
// Output: (N,1) float32 = segment_sum(edge_eng, edge_index[0]) + per_atom_energy

namespace {
constexpr float PZBL    = 0.23f;
constexpr float A0_INV  = 1.0f / 0.4685f;
constexpr float C1 = 0.02817f, C2 = 0.28022f, C3 = 0.50986f, C4 = 0.18175f;
constexpr float D1 = -0.20162f, D2 = -0.4029f, D3 = -0.94229f, D4 = -3.1998f;
constexpr float QQ      = 14.399645f * 0.5f;
constexpr float RMAX_INV = 1.0f / 6.0f;
}

// Tiny setup: 4-entry {Z, Z^0.23} table into workspace (d_ws is re-poisoned
// every call, so this must run every launch).
__global__ void zbl_table_kernel(const float* __restrict__ Z,
                                 float* __restrict__ tbl) {
    int t = threadIdx.x;
    if (t < 4) {
        float z = Z[t];
        tbl[t]     = z;
        tbl[4 + t] = powf(z, PZBL);
    }
}

// out = per_atom_energy (d_out is poisoned 0xAA before every timed call).
__global__ void zbl_init_out(const float* __restrict__ pae,
                             float* __restrict__ out, int n) {
    int i = blockIdx.x * blockDim.x + threadIdx.x;
    if (i < n) out[i] = pae[i];
}

__device__ __forceinline__ void zbl_one_edge(float rk, int ia, int ib,
                                             const int* __restrict__ types,
                                             const float* s_z, const float* s_zp,
                                             float* __restrict__ out) {
    float rr = rk * RMAX_INV;
    int ti = types[ia];
    int tj = types[ib];
    float zi = s_z[ti], zj = s_z[tj];
    float x = (s_zp[ti] + s_zp[tj]) * rk * A0_INV;
    float psi = C1 * __expf(D1 * x) + C2 * __expf(D2 * x)
              + C3 * __expf(D3 * x) + C4 * __expf(D4 * x);
    float eng = QQ * zi * zj * psi / rk;
    // p=6 polynomial cutoff: 1 - 28 rr^6 + 48 rr^7 - 21 rr^8
    float rr2 = rr * rr;
    float rr3 = rr2 * rr;
    float rr6 = rr3 * rr3;
    float cutoff = 1.0f + rr6 * (-28.0f + rr * (48.0f - 21.0f * rr));
    if (rr < 1.0f) {
        atomicAdd(&out[ia], cutoff * eng);
    }
}

__global__ __launch_bounds__(256) void zbl_edge_kernel(
    const float* __restrict__ r,
    const int*   __restrict__ ei0,   // edge_index row 0 (dest atoms)
    const int*   __restrict__ ei1,   // edge_index row 1
    const int*   __restrict__ types,
    const float* __restrict__ tbl,
    float*       __restrict__ out,
    int n_quads) {
    __shared__ float s_z[4];
    __shared__ float s_zp[4];
    if (threadIdx.x < 8) {
        if (threadIdx.x < 4) s_z[threadIdx.x] = tbl[threadIdx.x];
        else                 s_zp[threadIdx.x - 4] = tbl[threadIdx.x];
    }
    __syncthreads();

    int q = blockIdx.x * blockDim.x + threadIdx.x;
    if (q >= n_quads) return;

    float4 rv = ((const float4*)r)[q];
    int4   av = ((const int4*)ei0)[q];
    int4   bv = ((const int4*)ei1)[q];

    zbl_one_edge(rv.x, av.x, bv.x, types, s_z, s_zp, out);
    zbl_one_edge(rv.y, av.y, bv.y, types, s_z, s_zp, out);
    zbl_one_edge(rv.z, av.z, bv.z, types, s_z, s_zp, out);
    zbl_one_edge(rv.w, av.w, bv.w, types, s_z, s_zp, out);
}

// Scalar tail for n_edges % 4 != 0 (not hit for E = 6.4M, kept for generality).
__global__ void zbl_edge_tail(const float* __restrict__ r,
                              const int* __restrict__ ei0,
                              const int* __restrict__ ei1,
                              const int* __restrict__ types,
                              const float* __restrict__ tbl,
                              float* __restrict__ out,
                              int start, int n_edges) {
    __shared__ float s_z[4];
    __shared__ float s_zp[4];
    if (threadIdx.x < 8) {
        if (threadIdx.x < 4) s_z[threadIdx.x] = tbl[threadIdx.x];
        else                 s_zp[threadIdx.x - 4] = tbl[threadIdx.x];
    }
    __syncthreads();
    int e = start + threadIdx.x;
    if (e < n_edges) {
        zbl_one_edge(r[e], ei0[e], ei1[e], types, s_z, s_zp, out);
    }
}

extern "C" void kernel_launch(void* const* d_in, const int* in_sizes, int n_in,
                              void* d_out, int out_size, void* d_ws, size_t ws_size,
                              hipStream_t stream) {
    const float* Z     = (const float*)d_in[0];
    const float* r     = (const float*)d_in[1];
    const float* pae   = (const float*)d_in[2];
    const int*   types = (const int*)d_in[3];
    const int*   ei    = (const int*)d_in[4];

    const int n_edges = in_sizes[1];
    const int n_atoms = in_sizes[2];

    float* out = (float*)d_out;
    float* tbl = (float*)d_ws;

    // 1) {Z, Z^0.23} table (workspace re-poisoned each call -> recompute).
    zbl_table_kernel<<<1, 64, 0, stream>>>(Z, tbl);

    // 2) out = per_atom_energy (also the zero-init for the scatter-add).
    zbl_init_out<<<(n_atoms + 255) / 256, 256, 0, stream>>>(pae, out, n_atoms);

    // 3) Edge energies + atomic scatter-add, 4 edges/thread via 16B loads.
    const int n_quads = n_edges >> 2;
    if (n_quads > 0) {
        zbl_edge_kernel<<<(n_quads + 255) / 256, 256, 0, stream>>>(
            r, ei, ei + n_edges, types, tbl, out, n_quads);
    }
    const int rem = n_edges & 3;
    if (rem) {
        zbl_edge_tail<<<1, 64, 0, stream>>>(r, ei, ei + n_edges, types, tbl, out,
                                            n_edges - rem, n_edges);
    }
}

// Round 2
// 359.974 us; speedup vs baseline: 1.0225x; 1.0225x over previous
//
#include <hip/hip_runtime.h>

// ZBL pair potential + segment-sum into per-atom energies.
// Inputs (setup_inputs order):
//   d_in[0] Z            (4,)     float32
//   d_in[1] r            (E,)     float32   E = 6,400,000
//   d_in[2] per_atom_energy (N,1) float32   N = 100,000
//   d_in[3] atom_types   (N,)     int32
//   d_in[4] edge_index   (2,E)    int32
// Output: (N,1) float32 = segment_sum(edge_eng, edge_index[0]) + per_atom_energy
//
// R1 analysis: atomic-bound (VALUBusy 3.5%, WRITE_SIZE 163MB for a 0.4MB
// output => CAS-loop float atomics + hot-line contention). Fixes:
//  (a) unsafeAtomicAdd -> native global_atomic_add_f32 (no CAS retries)
//  (b) K=16 replica accumulators in d_ws, replica = blockIdx & 15, then a
//      reduce kernel out = pae + sum(copies). 16x more line parallelism.

namespace {
constexpr float PZBL     = 0.23f;
constexpr float A0_INV   = 1.0f / 0.4685f;
constexpr float C1 = 0.02817f, C2 = 0.28022f, C3 = 0.50986f, C4 = 0.18175f;
constexpr float D1 = -0.20162f, D2 = -0.4029f, D3 = -0.94229f, D4 = -3.1998f;
constexpr float QQ       = 14.399645f * 0.5f;
constexpr float RMAX_INV = 1.0f / 6.0f;
constexpr int   K_COPIES = 16;   // power of 2
}

// {Z, Z^0.23} table into workspace (ws re-poisoned every call -> recompute).
__global__ void zbl_table_kernel(const float* __restrict__ Z,
                                 float* __restrict__ tbl) {
    int t = threadIdx.x;
    if (t < 4) {
        float z = Z[t];
        tbl[t]     = z;
        tbl[4 + t] = powf(z, PZBL);
    }
}

// Fallback-path init: out = per_atom_energy.
__global__ void zbl_init_out(const float* __restrict__ pae,
                             float* __restrict__ out, int n) {
    int i = blockIdx.x * blockDim.x + threadIdx.x;
    if (i < n) out[i] = pae[i];
}

__device__ __forceinline__ void zbl_one_edge(float rk, int ia, int ib,
                                             const int* __restrict__ types,
                                             const float* s_z, const float* s_zp,
                                             float* __restrict__ dst) {
    float rr = rk * RMAX_INV;
    int ti = types[ia];
    int tj = types[ib];
    float zi = s_z[ti], zj = s_z[tj];
    float x = (s_zp[ti] + s_zp[tj]) * rk * A0_INV;
    float psi = C1 * __expf(D1 * x) + C2 * __expf(D2 * x)
              + C3 * __expf(D3 * x) + C4 * __expf(D4 * x);
    float eng = QQ * zi * zj * psi / rk;
    // p=6 polynomial cutoff: 1 - 28 rr^6 + 48 rr^7 - 21 rr^8
    float rr2 = rr * rr;
    float rr3 = rr2 * rr;
    float rr6 = rr3 * rr3;
    float cutoff = 1.0f + rr6 * (-28.0f + rr * (48.0f - 21.0f * rr));
    if (rr < 1.0f) {
        // Native global_atomic_add_f32 (no CAS loop). Rounding slop is fine:
        // absmax threshold is 1.7e3, we're at ~64.
        unsafeAtomicAdd(&dst[ia], cutoff * eng);
    }
}

__global__ __launch_bounds__(256) void zbl_edge_kernel(
    const float* __restrict__ r,
    const int*   __restrict__ ei0,   // edge_index row 0 (dest atoms)
    const int*   __restrict__ ei1,   // edge_index row 1
    const int*   __restrict__ types,
    const float* __restrict__ tbl,
    float*       __restrict__ copies,  // K replicas, each n_atoms floats
    int n_atoms, int k_mask,
    int n_quads) {
    __shared__ float s_z[4];
    __shared__ float s_zp[4];
    if (threadIdx.x < 8) {
        if (threadIdx.x < 4) s_z[threadIdx.x] = tbl[threadIdx.x];
        else                 s_zp[threadIdx.x - 4] = tbl[threadIdx.x];
    }
    __syncthreads();

    float* dst = copies + (size_t)(blockIdx.x & k_mask) * n_atoms;

    int q = blockIdx.x * blockDim.x + threadIdx.x;
    if (q >= n_quads) return;

    float4 rv = ((const float4*)r)[q];
    int4   av = ((const int4*)ei0)[q];
    int4   bv = ((const int4*)ei1)[q];

    zbl_one_edge(rv.x, av.x, bv.x, types, s_z, s_zp, dst);
    zbl_one_edge(rv.y, av.y, bv.y, types, s_z, s_zp, dst);
    zbl_one_edge(rv.z, av.z, bv.z, types, s_z, s_zp, dst);
    zbl_one_edge(rv.w, av.w, bv.w, types, s_z, s_zp, dst);
}

// Scalar tail for n_edges % 4 != 0 (not hit for E = 6.4M).
__global__ void zbl_edge_tail(const float* __restrict__ r,
                              const int* __restrict__ ei0,
                              const int* __restrict__ ei1,
                              const int* __restrict__ types,
                              const float* __restrict__ tbl,
                              float* __restrict__ dst,
                              int start, int n_edges) {
    __shared__ float s_z[4];
    __shared__ float s_zp[4];
    if (threadIdx.x < 8) {
        if (threadIdx.x < 4) s_z[threadIdx.x] = tbl[threadIdx.x];
        else                 s_zp[threadIdx.x - 4] = tbl[threadIdx.x];
    }
    __syncthreads();
    int e = start + threadIdx.x;
    if (e < n_edges) {
        zbl_one_edge(r[e], ei0[e], ei1[e], types, s_z, s_zp, dst);
    }
}

// out = pae + sum over K copies. Coalesced reads; ~6.8 MB total traffic.
__global__ void zbl_reduce_out(const float* __restrict__ pae,
                               const float* __restrict__ copies,
                               float* __restrict__ out,
                               int n, int k) {
    int i = blockIdx.x * blockDim.x + threadIdx.x;
    if (i >= n) return;
    float s = pae[i];
    for (int c = 0; c < k; ++c) s += copies[(size_t)c * n + i];
    out[i] = s;
}

extern "C" void kernel_launch(void* const* d_in, const int* in_sizes, int n_in,
                              void* d_out, int out_size, void* d_ws, size_t ws_size,
                              hipStream_t stream) {
    const float* Z     = (const float*)d_in[0];
    const float* r     = (const float*)d_in[1];
    const float* pae   = (const float*)d_in[2];
    const int*   types = (const int*)d_in[3];
    const int*   ei    = (const int*)d_in[4];

    const int n_edges = in_sizes[1];
    const int n_atoms = in_sizes[2];

    float* out = (float*)d_out;
    float* tbl = (float*)d_ws;
    float* copies = tbl + 8;

    // Pick replica count that fits the workspace (8 floats reserved for tbl).
    int K = K_COPIES;
    while (K > 1 && (8 + (size_t)K * n_atoms) * sizeof(float) > ws_size) K >>= 1;
    const bool use_copies = (8 + (size_t)K * n_atoms) * sizeof(float) <= ws_size;

    zbl_table_kernel<<<1, 64, 0, stream>>>(Z, tbl);

    const int n_quads = n_edges >> 2;
    const int rem     = n_edges & 3;

    if (use_copies) {
        hipMemsetAsync(copies, 0, (size_t)K * n_atoms * sizeof(float), stream);
        if (n_quads > 0) {
            zbl_edge_kernel<<<(n_quads + 255) / 256, 256, 0, stream>>>(
                r, ei, ei + n_edges, types, tbl, copies, n_atoms, K - 1, n_quads);
        }
        if (rem) {
            zbl_edge_tail<<<1, 64, 0, stream>>>(r, ei, ei + n_edges, types, tbl,
                                                copies, n_edges - rem, n_edges);
        }
        zbl_reduce_out<<<(n_atoms + 255) / 256, 256, 0, stream>>>(
            pae, copies, out, n_atoms, K);
    } else {
        // Workspace too small: accumulate directly into out (R1 behavior,
        // but with native atomics).
        zbl_init_out<<<(n_atoms + 255) / 256, 256, 0, stream>>>(pae, out, n_atoms);
        if (n_quads > 0) {
            zbl_edge_kernel<<<(n_quads + 255) / 256, 256, 0, stream>>>(
                r, ei, ei + n_edges, types, tbl, out, n_atoms, 0, n_quads);
        }
        if (rem) {
            zbl_edge_tail<<<1, 64, 0, stream>>>(r, ei, ei + n_edges, types, tbl,
                                                out, n_edges - rem, n_edges);
        }
    }
}